// Round 9
// baseline (351.455 us; speedup 1.0000x reference)
//
#include <hip/hip_runtime.h>
#include <hip/hip_bf16.h>

// Conv2d NCHW, stride=1, pad=1, N=16, C=8, K=8, H=W=1024, 3x3, fp32 in/out.
// Round 9: pipelined strips. Verified MFMA implicit GEMM (absmax 0.031) kept;
// structure: 512-thr blocks, 8 h-tiles per block (strip), double-buffered LDS,
// one barrier/tile, next-tile global loads issued BEFORE compute so HBM
// latency hides under ds_read+MFMA+stores (T14). WB=128 -> GX=8, no overlap
// blocks, all 8 w-tiles stored. Grid 2048 = 2 blocks/CU x 4 exact fills.

typedef __attribute__((ext_vector_type(8))) short short8;
typedef __attribute__((ext_vector_type(4))) float f32x4;

#define HH 1024
#define WW 1024
#define HWsz (1024*1024)
#define WB 128          // output cols per tile
#define HB 8            // output rows per tile
#define SROWS 10        // staged rows per tile
#define SW 136          // staged cols: w0-4 .. w0+131
#define UROW 137        // 16B units per LDS row (136 + 1 pad)
#define TPR 34          // staging tiles per row
#define NTILES (SROWS*TPR)   // 340
#define NIT 8           // h-tiles per strip (block)
#define GX 8            // 1024/WB
#define NSTRIP 16       // 1024/(HB*NIT)
#define NBLK (GX*NSTRIP*16)  // 2048 = 8 XCD x 256

__device__ __forceinline__ int pk2(float a, float b) {
    __hip_bfloat162 h = __float22bfloat162_rn(make_float2(a, b));  // v_cvt_pk_bf16_f32
    return *reinterpret_cast<int*>(&h);
}
__device__ __forceinline__ unsigned short f2bf(float f) {
    unsigned u = __float_as_uint(f);
    return (unsigned short)((u + 0x7FFFu + ((u >> 16) & 1u)) >> 16);   // RNE
}

__global__ __launch_bounds__(512, 4) void conv3x3_mfma_pipe(
    const float* __restrict__ x,      // [16][8][1024][1024]
    const float* __restrict__ wgt,    // [8][8][3][3]
    const float* __restrict__ bias,   // [8]
    float* __restrict__ out)          // [16][8][1024][1024]
{
    __shared__ int4 lds[2 * SROWS * UROW];

    const int tid  = threadIdx.x;
    const int lane = tid & 63;
    const int wv   = tid >> 6;        // wave 0..7 = output row within tile
    const int l15  = lane & 15;
    const int ch   = lane >> 4;

    // ---- XCD swizzle + decode: 2048 = 8 x 256; per XCD: 2 n-planes ----
    const unsigned bid  = blockIdx.x;
    const unsigned work = (bid & 7u) * (NBLK / 8u) + (bid >> 3);
    const int n     = (int)(work >> 7);          // /(GX*NSTRIP)
    const unsigned rem = work & 127u;
    const int wx    = (int)(rem >> 4);
    const int strip = (int)(rem & 15u);
    const int w0    = wx * WB;
    const int hbase = strip * (HB * NIT);        // strip*64

    const float* xn = x + (size_t)n * 8 * HWsz;

    // ---- per-lane tap -> LDS unit offsets ----
    const int t0  = ch;                          // taps 0..3 (MFMA 0)
    const int kh0 = (t0 >= 3) ? 1 : 0;
    const int kw0 = t0 - 3 * kh0;
    const int t1  = 4 + ch;                      // taps 4..7 (MFMA 1)
    const int kh1 = (t1 >= 6) ? 2 : 1;
    const int kw1 = t1 - 3 * kh1;
    const int off0 = kh0 * UROW + kw0 + 3;
    const int off1 = kh1 * UROW + kw1 + 3;
    const int off2 = 2 * UROW + 2 + 3;           // tap 8 (2,2)

    // ---- weight B-fragments (built once per block) ----
    const int  coc = (l15 < 8) ? l15 : 7;
    const bool com = (l15 < 8);
    short8 b0, b1, b2;
    {
        const float* wp0 = wgt + coc * 72 + kh0 * 3 + kw0;
        const float* wp1 = wgt + coc * 72 + kh1 * 3 + kw1;
        const float* wp2 = wgt + coc * 72 + 2 * 3 + 2;
#pragma unroll
        for (int j = 0; j < 8; ++j) {
            b0[j] = (short)(com ? f2bf(wp0[j * 9]) : 0);
            b1[j] = (short)(com ? f2bf(wp1[j * 9]) : 0);
            b2[j] = (short)((com && ch == 0) ? f2bf(wp2[j * 9]) : 0);
        }
    }
    const float bv = com ? bias[l15] : 0.0f;

    // ---- staging thread constants (1 tile per thread, tid<340) ----
    const bool st   = (tid < NTILES);
    const int  srow = st ? (tid / TPR) : 0;
    const int  swt  = st ? (tid - srow * TPR) : 0;
    const int  gw0  = w0 - 4 + swt * 4;                     // mult of 4
    const bool wok  = ((unsigned)gw0 < (unsigned)WW);       // <=1020 ok

    f32x4 v0, v1, v2, v3, v4, v5, v6, v7;

    auto LOADT = [&](int it) {
        if (st) {
            const int gh = hbase + it * HB - 1 + srow;
            if (wok && (unsigned)gh < (unsigned)HH) {
                const float* p = xn + (size_t)gh * WW + gw0;
                v0 = *reinterpret_cast<const f32x4*>(p + 0 * (size_t)HWsz);
                v1 = *reinterpret_cast<const f32x4*>(p + 1 * (size_t)HWsz);
                v2 = *reinterpret_cast<const f32x4*>(p + 2 * (size_t)HWsz);
                v3 = *reinterpret_cast<const f32x4*>(p + 3 * (size_t)HWsz);
                v4 = *reinterpret_cast<const f32x4*>(p + 4 * (size_t)HWsz);
                v5 = *reinterpret_cast<const f32x4*>(p + 5 * (size_t)HWsz);
                v6 = *reinterpret_cast<const f32x4*>(p + 6 * (size_t)HWsz);
                v7 = *reinterpret_cast<const f32x4*>(p + 7 * (size_t)HWsz);
            } else {
                v0 = v1 = v2 = v3 = v4 = v5 = v6 = v7 = (f32x4)0.0f;
            }
        }
    };

    auto WRITET = [&](int bufsel) {
        if (st) {
            int4* dst = &lds[bufsel * (SROWS * UROW) + srow * UROW + swt * 4];
#pragma unroll
            for (int q = 0; q < 4; ++q) {
                int4 pk;
                pk.x = pk2(v0[q], v1[q]);
                pk.y = pk2(v2[q], v3[q]);
                pk.z = pk2(v4[q], v5[q]);
                pk.w = pk2(v6[q], v7[q]);
                dst[q] = pk;
            }
        }
    };

    // ---- pipelined strip loop ----
    LOADT(0);
    for (int it = 0; it < NIT; ++it) {
        WRITET(it & 1);
        __syncthreads();
        if (it + 1 < NIT) LOADT(it + 1);        // fly under compute

        const int4* B = &lds[(it & 1) * (SROWS * UROW)];
        f32x4 acc[8];
#pragma unroll
        for (int wt = 0; wt < 8; ++wt) {
            acc[wt].x = bv; acc[wt].y = bv; acc[wt].z = bv; acc[wt].w = bv;
        }
        const int ubase = wv * UROW + l15;
#pragma unroll
        for (int wt = 0; wt < 8; ++wt) {
            const int u = ubase + wt * 16;
            short8 a0 = *reinterpret_cast<const short8*>(&B[u + off0]);
            short8 a1 = *reinterpret_cast<const short8*>(&B[u + off1]);
            short8 a2 = *reinterpret_cast<const short8*>(&B[u + off2]);
            f32x4 c = acc[wt];
            c = __builtin_amdgcn_mfma_f32_16x16x32_bf16(a0, b0, c, 0, 0, 0);
            c = __builtin_amdgcn_mfma_f32_16x16x32_bf16(a1, b1, c, 0, 0, 0);
            c = __builtin_amdgcn_mfma_f32_16x16x32_bf16(a2, b2, c, 0, 0, 0);
            acc[wt] = c;
        }

        if (com) {
            float* op = out + ((size_t)n * 8 + l15) * HWsz
                            + (size_t)(hbase + it * HB + wv) * WW + w0 + ch * 4;
#pragma unroll
            for (int wt = 0; wt < 8; ++wt)
                *reinterpret_cast<float4*>(op + wt * 16) =
                    *reinterpret_cast<const float4*>(&acc[wt]);
        }
    }
}

extern "C" void kernel_launch(void* const* d_in, const int* in_sizes, int n_in,
                              void* d_out, int out_size, void* d_ws, size_t ws_size,
                              hipStream_t stream) {
    const float* x    = (const float*)d_in[0];
    const float* wgt  = (const float*)d_in[1];
    const float* bias = (const float*)d_in[2];
    float* out = (float*)d_out;

    dim3 grid(NBLK, 1, 1);
    dim3 block(512, 1, 1);
    conv3x3_mfma_pipe<<<grid, block, 0, stream>>>(x, wgt, bias, out);
}